// Round 11
// baseline (2568.274 us; speedup 1.0000x reference)
//
#include <hip/hip_runtime.h>
#include <math.h>

#define NE 1000000
#define DD 128
#define TWOD 256
#define H1C 256
#define H2C 128
#define EB 64            // 16 edges per wave, wave-private rows: no block barriers
#define EPSLN 1e-5f

typedef float f32x2 __attribute__((ext_vector_type(2)));
typedef float f32x4 __attribute__((ext_vector_type(4)));

#define LO2(q) __builtin_shufflevector((q), (q), 0, 1)
#define HI2(q) __builtin_shufflevector((q), (q), 2, 3)

// c += broadcast(x.lo) * w
__device__ __forceinline__ void pk_fma_b0(f32x2& c, f32x2 x, f32x2 w) {
    asm("v_pk_fma_f32 %0, %1, %2, %0 op_sel:[0,0,0] op_sel_hi:[0,1,1]"
        : "+v"(c) : "v"(x), "v"(w));
}
// c += broadcast(x.hi) * w
__device__ __forceinline__ void pk_fma_b1(f32x2& c, f32x2 x, f32x2 w) {
    asm("v_pk_fma_f32 %0, %1, %2, %0 op_sel:[1,0,0] op_sel_hi:[1,1,1]"
        : "+v"(c) : "v"(x), "v"(w));
}

__global__ __launch_bounds__(256, 2)
void decoder_fused(const float* __restrict__ nodes,
                   const float* __restrict__ nbrs,
                   const int*   __restrict__ eidx,
                   const float* __restrict__ g0, const float* __restrict__ be0,
                   const float* __restrict__ W1, const float* __restrict__ b1,
                   const float* __restrict__ g1, const float* __restrict__ be1,
                   const float* __restrict__ W2, const float* __restrict__ b2,
                   const float* __restrict__ g2, const float* __restrict__ be2,
                   const float* __restrict__ Wp, const float* __restrict__ bp,
                   const float* __restrict__ Ww, const float* __restrict__ bw,
                   const float* __restrict__ wnode, const float* __restrict__ wnbr,
                   float* __restrict__ out)
{
    __shared__ __align__(16) float xb[EB][TWOD];   // rows 16wv..16wv+15 private to wave wv
    __shared__ float nbsim[EB];

    const int t    = threadIdx.x;
    const int wv   = t >> 6;     // wave 0..3
    const int lane = t & 63;
    const int e0   = blockIdx.x * EB;
    const int r0   = wv * 16;    // wave's 16 rows; EVERY lane works on all 16

    // ------- Stage 1 (bit-exact w16 form, R8-proven): 16 lanes/edge ----------
    {
        const int grp = lane >> 4;   // 0..3
        const int gl  = lane & 15;   // 0..15
        const int d0  = gl * 8;
        const f32x4 g0s0 = *(const f32x4*)(g0  + d0);
        const f32x4 g0s1 = *(const f32x4*)(g0  + d0 + 4);
        const f32x4 g0p0 = *(const f32x4*)(g0  + DD + d0);
        const f32x4 g0p1 = *(const f32x4*)(g0  + DD + d0 + 4);
        const f32x4 e0s0 = *(const f32x4*)(be0 + d0);
        const f32x4 e0s1 = *(const f32x4*)(be0 + d0 + 4);
        const f32x4 e0p0 = *(const f32x4*)(be0 + DD + d0);
        const f32x4 e0p1 = *(const f32x4*)(be0 + DD + d0 + 4);
        #pragma unroll
        for (int rr = 0; rr < 4; ++rr) {
            const int el = wv * 16 + rr * 4 + grp;
            const int e  = e0 + el;
            const int u  = eidx[e];
            const int v  = eidx[NE + e];
            const f32x4 nu0 = *(const f32x4*)(nodes + u * DD + d0);
            const f32x4 nu1 = *(const f32x4*)(nodes + u * DD + d0 + 4);
            const f32x4 nv0 = *(const f32x4*)(nodes + v * DD + d0);
            const f32x4 nv1 = *(const f32x4*)(nodes + v * DD + d0 + 4);
            const f32x4 bu0 = *(const f32x4*)(nbrs  + u * DD + d0);
            const f32x4 bu1 = *(const f32x4*)(nbrs  + u * DD + d0 + 4);
            const f32x4 bv0 = *(const f32x4*)(nbrs  + v * DD + d0);
            const f32x4 bv1 = *(const f32x4*)(nbrs  + v * DD + d0 + 4);
            float s[8], p[8], bu[8], bv[8];
            #pragma unroll
            for (int j = 0; j < 4; ++j) {
                s[j]     = nu0[j] + nv0[j];  p[j]     = nu0[j] * nv0[j];
                s[4 + j] = nu1[j] + nv1[j];  p[4 + j] = nu1[j] * nv1[j];
                bu[j] = bu0[j]; bu[4 + j] = bu1[j];
                bv[j] = bv0[j]; bv[4 + j] = bv1[j];
            }
            float ps_[4], pss_[4], pd_[4];
            #pragma unroll
            for (int jj = 0; jj < 4; ++jj) {
                const float sx = s[2*jj], sy = s[2*jj+1];
                const float px = p[2*jj], py = p[2*jj+1];
                ps_[jj]  = ((sx + sy) + px) + py;
                pss_[jj] = ((sx*sx + sy*sy) + px*px) + py*py;
                pd_[jj]  = bu[2*jj]*bv[2*jj] + bu[2*jj+1]*bv[2*jj+1];
            }
            float ps  = (ps_[0]  + ps_[1])  + (ps_[2]  + ps_[3]);
            float pss = (pss_[0] + pss_[1]) + (pss_[2] + pss_[3]);
            float pd  = (pd_[0]  + pd_[1])  + (pd_[2]  + pd_[3]);
            #pragma unroll
            for (int m = 1; m < 16; m <<= 1) {
                ps  += __shfl_xor(ps,  m, 16);
                pss += __shfl_xor(pss, m, 16);
                pd  += __shfl_xor(pd,  m, 16);
            }
            const float mu  = ps  * (1.0f / 256.0f);
            const float var = pss * (1.0f / 256.0f) - mu * mu;
            const float inv = 1.0f / sqrtf(var + EPSLN);
            f32x4 os0, os1, op0, op1;
            #pragma unroll
            for (int j = 0; j < 4; ++j) {
                os0[j] = (s[j]     - mu) * inv * g0s0[j] + e0s0[j];
                os1[j] = (s[4 + j] - mu) * inv * g0s1[j] + e0s1[j];
                op0[j] = (p[j]     - mu) * inv * g0p0[j] + e0p0[j];
                op1[j] = (p[4 + j] - mu) * inv * g0p1[j] + e0p1[j];
            }
            *(f32x4*)&xb[el][d0]          = os0;
            *(f32x4*)&xb[el][d0 + 4]      = os1;
            *(f32x4*)&xb[el][DD + d0]     = op0;
            *(f32x4*)&xb[el][DD + d0 + 4] = op1;
            if (gl == 0) nbsim[el] = pd;
        }
    }
    __builtin_amdgcn_wave_barrier();   // fence: stage-1 writes before GEMM1 reads

    // ------- GEMM1: full-wave cols (4/lane, no dup W), 16 rows/thread --------
    f32x2 acc1[16][2];
    #pragma unroll
    for (int i = 0; i < 16; ++i) {
        acc1[i][0] = f32x2{0.0f, 0.0f};
        acc1[i][1] = f32x2{0.0f, 0.0f};
    }

    const int c1 = lane * 4;
    {
        const float* __restrict__ w1p = W1 + c1;
        #pragma unroll 2
        for (int k0 = 0; k0 < TWOD; k0 += 4) {
            // 4 VMEM loads per chunk (was 8): one quad per k-row, unique cols
            const float* wp = w1p + k0 * H1C;
            const f32x4 w0 = *(const f32x4*)(wp);
            const f32x4 w1 = *(const f32x4*)(wp + H1C);
            const f32x4 w2 = *(const f32x4*)(wp + 2 * H1C);
            const f32x4 w3 = *(const f32x4*)(wp + 3 * H1C);
            const f32x2 w0a = LO2(w0), w0b = HI2(w0);
            const f32x2 w1a = LO2(w1), w1b = HI2(w1);
            const f32x2 w2a = LO2(w2), w2b = HI2(w2);
            const f32x2 w3a = LO2(w3), w3b = HI2(w3);
            #pragma unroll
            for (int hh = 0; hh < 2; ++hh) {
                f32x2 xp0[8], xp1[8];
                #pragma unroll
                for (int i = 0; i < 8; ++i) {   // all-lane broadcast reads
                    f32x4 q = *(const f32x4*)&xb[r0 + hh * 8 + i][k0];
                    xp0[i] = LO2(q); xp1[i] = HI2(q);
                }
                #pragma unroll
                for (int i = 0; i < 8; ++i) {
                    const int ri = hh * 8 + i;
                    pk_fma_b0(acc1[ri][0], xp0[i], w0a);
                    pk_fma_b0(acc1[ri][1], xp0[i], w0b);
                    pk_fma_b1(acc1[ri][0], xp0[i], w1a);
                    pk_fma_b1(acc1[ri][1], xp0[i], w1b);
                    pk_fma_b0(acc1[ri][0], xp1[i], w2a);
                    pk_fma_b0(acc1[ri][1], xp1[i], w2b);
                    pk_fma_b1(acc1[ri][0], xp1[i], w3a);
                    pk_fma_b1(acc1[ri][1], xp1[i], w3b);
                }
            }
        }
    }
    __builtin_amdgcn_wave_barrier();   // fence: GEMM1 reads before LN1 writes

    // ------- bias + LN1 + ReLU: 4 cols/lane, w64 tree, 16 rows ---------------
    {
        const f32x4 b1q = *(const f32x4*)(b1  + c1);
        const f32x4 g1q = *(const f32x4*)(g1  + c1);
        const f32x4 e1q = *(const f32x4*)(be1 + c1);
        #pragma unroll
        for (int i = 0; i < 16; ++i) {
            const float v0 = acc1[i][0].x + b1q[0];
            const float v1 = acc1[i][0].y + b1q[1];
            const float v2 = acc1[i][1].x + b1q[2];
            const float v3 = acc1[i][1].y + b1q[3];
            float s  = (v0 + v1) + (v2 + v3);
            float ss = (v0*v0 + v1*v1) + (v2*v2 + v3*v3);
            #pragma unroll
            for (int m = 1; m < 64; m <<= 1) {
                s  += __shfl_xor(s,  m, 64);
                ss += __shfl_xor(ss, m, 64);
            }
            const float mu  = s  * (1.0f / 256.0f);
            const float var = ss * (1.0f / 256.0f) - mu * mu;
            const float inv = 1.0f / sqrtf(var + EPSLN);
            f32x4 o;
            o[0] = fmaxf(0.0f, (v0 - mu) * inv * g1q[0] + e1q[0]);
            o[1] = fmaxf(0.0f, (v1 - mu) * inv * g1q[1] + e1q[1]);
            o[2] = fmaxf(0.0f, (v2 - mu) * inv * g1q[2] + e1q[2]);
            o[3] = fmaxf(0.0f, (v3 - mu) * inv * g1q[3] + e1q[3]);
            *(f32x4*)&xb[r0 + i][c1] = o;
        }
    }
    __builtin_amdgcn_wave_barrier();   // fence: LN1 writes before GEMM2 reads

    // ------- GEMM2: full-wave cols (2/lane), 16 rows/thread ------------------
    f32x2 acc2[16];
    #pragma unroll
    for (int i = 0; i < 16; ++i) acc2[i] = f32x2{0.0f, 0.0f};

    const int c2 = lane * 2;
    {
        const float* __restrict__ w2p = W2 + c2;
        #pragma unroll 2
        for (int k0 = 0; k0 < TWOD; k0 += 4) {
            const float* wp = w2p + k0 * H2C;
            const f32x2 d0 = *(const f32x2*)(wp);
            const f32x2 d1 = *(const f32x2*)(wp + H2C);
            const f32x2 d2 = *(const f32x2*)(wp + 2 * H2C);
            const f32x2 d3 = *(const f32x2*)(wp + 3 * H2C);
            #pragma unroll
            for (int hh = 0; hh < 2; ++hh) {
                f32x2 xp0[8], xp1[8];
                #pragma unroll
                for (int i = 0; i < 8; ++i) {
                    f32x4 q = *(const f32x4*)&xb[r0 + hh * 8 + i][k0];
                    xp0[i] = LO2(q); xp1[i] = HI2(q);
                }
                #pragma unroll
                for (int i = 0; i < 8; ++i) {
                    const int ri = hh * 8 + i;
                    pk_fma_b0(acc2[ri], xp0[i], d0);
                    pk_fma_b1(acc2[ri], xp0[i], d1);
                    pk_fma_b0(acc2[ri], xp1[i], d2);
                    pk_fma_b1(acc2[ri], xp1[i], d3);
                }
            }
        }
    }

    // ------- bias + LN2 + ReLU + heads + outputs: 2 cols/lane, w64 tree ------
    {
        const f32x2 b2v = *(const f32x2*)(b2  + c2);
        const f32x2 g2v = *(const f32x2*)(g2  + c2);
        const f32x2 e2v = *(const f32x2*)(be2 + c2);
        const f32x2 wpv = *(const f32x2*)(Wp  + c2);
        const f32x2 wwv = *(const f32x2*)(Ww  + c2);
        const float ww128 = Ww[DD];
        const float bpv = bp[0], bwv = bw[0];
        const float wn = wnode[0], wbr = wnbr[0];
        #pragma unroll
        for (int i = 0; i < 16; ++i) {
            const float v0 = acc2[i].x + b2v.x;
            const float v1 = acc2[i].y + b2v.y;
            float s  = v0 + v1;
            float ss = v0*v0 + v1*v1;
            #pragma unroll
            for (int m = 1; m < 64; m <<= 1) {
                s  += __shfl_xor(s,  m, 64);
                ss += __shfl_xor(ss, m, 64);
            }
            const float mu  = s  * (1.0f / 128.0f);
            const float var = ss * (1.0f / 128.0f) - mu * mu;
            const float inv = 1.0f / sqrtf(var + EPSLN);
            const float h0 = fmaxf(0.0f, (v0 - mu) * inv * g2v.x + e2v.x);
            const float h1 = fmaxf(0.0f, (v1 - mu) * inv * g2v.y + e2v.y);
            float pdot = h0 * wpv.x + h1 * wpv.y;
            float wdot = h0 * wwv.x + h1 * wwv.y;
            #pragma unroll
            for (int m = 1; m < 64; m <<= 1) {
                pdot += __shfl_xor(pdot, m, 64);
                wdot += __shfl_xor(wdot, m, 64);
            }
            if (lane == 0) {
                const int e  = e0 + r0 + i;
                const float ns   = nbsim[r0 + i];
                const float nc   = (pdot + bpv) * wn;
                const float nbc  = ns * wbr;
                const float prob = nc + nbc;
                out[e]          = prob;
                out[NE + e]     = fmaxf(0.0f, wdot + ns * ww128 + bwv);
                out[2 * NE + e] = nc / (prob + 1e-8f);
            }
        }
    }
}

extern "C" void kernel_launch(void* const* d_in, const int* in_sizes, int n_in,
                              void* d_out, int out_size, void* d_ws, size_t ws_size,
                              hipStream_t stream) {
    const float* nodes = (const float*)d_in[0];
    const float* nbrs  = (const float*)d_in[1];
    const int*   eidx  = (const int*)d_in[2];
    const float* g0    = (const float*)d_in[3];
    const float* be0   = (const float*)d_in[4];
    const float* W1    = (const float*)d_in[5];
    const float* b1    = (const float*)d_in[6];
    const float* g1    = (const float*)d_in[7];
    const float* be1   = (const float*)d_in[8];
    const float* W2    = (const float*)d_in[9];
    const float* b2    = (const float*)d_in[10];
    const float* g2    = (const float*)d_in[11];
    const float* be2   = (const float*)d_in[12];
    const float* Wp    = (const float*)d_in[13];
    const float* bp    = (const float*)d_in[14];
    const float* Ww    = (const float*)d_in[15];
    const float* bw    = (const float*)d_in[16];
    const float* wnode = (const float*)d_in[17];
    const float* wnbr  = (const float*)d_in[18];
    float* out = (float*)d_out;

    dim3 grid(NE / EB), block(256);
    decoder_fused<<<grid, block, 0, stream>>>(nodes, nbrs, eidx, g0, be0,
                                              W1, b1, g1, be1, W2, b2, g2, be2,
                                              Wp, bp, Ww, bw, wnode, wnbr, out);
}

// Round 12
// 2426.936 us; speedup vs baseline: 1.0582x; 1.0582x over previous
//
#include <hip/hip_runtime.h>
#include <math.h>

#define NE 1000000
#define DD 128
#define TWOD 256
#define H1C 256
#define H2C 128
#define EB 64            // 16 edges per wave, wave-private rows: no block barriers
#define EPSLN 1e-5f

typedef float f32x2 __attribute__((ext_vector_type(2)));
typedef float f32x4 __attribute__((ext_vector_type(4)));

#define LO2(q) __builtin_shufflevector((q), (q), 0, 1)
#define HI2(q) __builtin_shufflevector((q), (q), 2, 3)

// c += broadcast(x.lo) * w
__device__ __forceinline__ void pk_fma_b0(f32x2& c, f32x2 x, f32x2 w) {
    asm("v_pk_fma_f32 %0, %1, %2, %0 op_sel:[0,0,0] op_sel_hi:[0,1,1]"
        : "+v"(c) : "v"(x), "v"(w));
}
// c += broadcast(x.hi) * w
__device__ __forceinline__ void pk_fma_b1(f32x2& c, f32x2 x, f32x2 w) {
    asm("v_pk_fma_f32 %0, %1, %2, %0 op_sel:[1,0,0] op_sel_hi:[1,1,1]"
        : "+v"(c) : "v"(x), "v"(w));
}

__global__ __launch_bounds__(256, 2)
void decoder_fused(const float* __restrict__ nodes,
                   const float* __restrict__ nbrs,
                   const int*   __restrict__ eidx,
                   const float* __restrict__ g0, const float* __restrict__ be0,
                   const float* __restrict__ W1, const float* __restrict__ b1,
                   const float* __restrict__ g1, const float* __restrict__ be1,
                   const float* __restrict__ W2, const float* __restrict__ b2,
                   const float* __restrict__ g2, const float* __restrict__ be2,
                   const float* __restrict__ Wp, const float* __restrict__ bp,
                   const float* __restrict__ Ww, const float* __restrict__ bw,
                   const float* __restrict__ wnode, const float* __restrict__ wnbr,
                   float* __restrict__ out)
{
    __shared__ __align__(16) float xb[EB][TWOD];   // rows 16wv..16wv+15 private to wave wv
    __shared__ float nbsim[EB];

    const int t    = threadIdx.x;
    const int wv   = t >> 6;     // wave 0..3
    const int lane = t & 63;
    const int cb   = lane & 31;  // col block 0..31
    const int e0   = blockIdx.x * EB;
    const int r0   = wv * 16 + (lane >> 5) * 8;   // this thread's 8 rows (GEMM phases)

    // ------- Stage 1 (bit-exact w16 form): 16 lanes/edge, 4 edges/round ------
    {
        const int grp = lane >> 4;   // 0..3
        const int gl  = lane & 15;   // 0..15
        const int d0  = gl * 8;
        const f32x4 g0s0 = *(const f32x4*)(g0  + d0);
        const f32x4 g0s1 = *(const f32x4*)(g0  + d0 + 4);
        const f32x4 g0p0 = *(const f32x4*)(g0  + DD + d0);
        const f32x4 g0p1 = *(const f32x4*)(g0  + DD + d0 + 4);
        const f32x4 e0s0 = *(const f32x4*)(be0 + d0);
        const f32x4 e0s1 = *(const f32x4*)(be0 + d0 + 4);
        const f32x4 e0p0 = *(const f32x4*)(be0 + DD + d0);
        const f32x4 e0p1 = *(const f32x4*)(be0 + DD + d0 + 4);
        #pragma unroll
        for (int rr = 0; rr < 4; ++rr) {
            const int el = wv * 16 + rr * 4 + grp;
            const int e  = e0 + el;
            const int u  = eidx[e];
            const int v  = eidx[NE + e];
            const f32x4 nu0 = *(const f32x4*)(nodes + u * DD + d0);
            const f32x4 nu1 = *(const f32x4*)(nodes + u * DD + d0 + 4);
            const f32x4 nv0 = *(const f32x4*)(nodes + v * DD + d0);
            const f32x4 nv1 = *(const f32x4*)(nodes + v * DD + d0 + 4);
            const f32x4 bu0 = *(const f32x4*)(nbrs  + u * DD + d0);
            const f32x4 bu1 = *(const f32x4*)(nbrs  + u * DD + d0 + 4);
            const f32x4 bv0 = *(const f32x4*)(nbrs  + v * DD + d0);
            const f32x4 bv1 = *(const f32x4*)(nbrs  + v * DD + d0 + 4);
            float s[8], p[8], bu[8], bv[8];
            #pragma unroll
            for (int j = 0; j < 4; ++j) {
                s[j]     = nu0[j] + nv0[j];  p[j]     = nu0[j] * nv0[j];
                s[4 + j] = nu1[j] + nv1[j];  p[4 + j] = nu1[j] * nv1[j];
                bu[j] = bu0[j]; bu[4 + j] = bu1[j];
                bv[j] = bv0[j]; bv[4 + j] = bv1[j];
            }
            float ps_[4], pss_[4], pd_[4];
            #pragma unroll
            for (int jj = 0; jj < 4; ++jj) {
                const float sx = s[2*jj], sy = s[2*jj+1];
                const float px = p[2*jj], py = p[2*jj+1];
                ps_[jj]  = ((sx + sy) + px) + py;
                pss_[jj] = ((sx*sx + sy*sy) + px*px) + py*py;
                pd_[jj]  = bu[2*jj]*bv[2*jj] + bu[2*jj+1]*bv[2*jj+1];
            }
            float ps  = (ps_[0]  + ps_[1])  + (ps_[2]  + ps_[3]);
            float pss = (pss_[0] + pss_[1]) + (pss_[2] + pss_[3]);
            float pd  = (pd_[0]  + pd_[1])  + (pd_[2]  + pd_[3]);
            #pragma unroll
            for (int m = 1; m < 16; m <<= 1) {
                ps  += __shfl_xor(ps,  m, 16);
                pss += __shfl_xor(pss, m, 16);
                pd  += __shfl_xor(pd,  m, 16);
            }
            const float mu  = ps  * (1.0f / 256.0f);
            const float var = pss * (1.0f / 256.0f) - mu * mu;
            const float inv = 1.0f / sqrtf(var + EPSLN);
            f32x4 os0, os1, op0, op1;
            #pragma unroll
            for (int j = 0; j < 4; ++j) {
                os0[j] = (s[j]     - mu) * inv * g0s0[j] + e0s0[j];
                os1[j] = (s[4 + j] - mu) * inv * g0s1[j] + e0s1[j];
                op0[j] = (p[j]     - mu) * inv * g0p0[j] + e0p0[j];
                op1[j] = (p[4 + j] - mu) * inv * g0p1[j] + e0p1[j];
            }
            *(f32x4*)&xb[el][d0]          = os0;
            *(f32x4*)&xb[el][d0 + 4]      = os1;
            *(f32x4*)&xb[el][DD + d0]     = op0;
            *(f32x4*)&xb[el][DD + d0 + 4] = op1;
            if (gl == 0) nbsim[el] = pd;
        }
    }
    __builtin_amdgcn_wave_barrier();   // fence: stage-1 writes before GEMM1 reads

    // ---------------- GEMM1: 8 rows x 8 cols (R8-proven) ---------------------
    f32x2 acc1[8][4];
    #pragma unroll
    for (int i = 0; i < 8; ++i)
        #pragma unroll
        for (int p = 0; p < 4; ++p) acc1[i][p] = f32x2{0.0f, 0.0f};

    const int c1 = cb * 8;
    {
        const float* __restrict__ w1p = W1 + c1;
        f32x4 c00 = *(const f32x4*)(w1p);
        f32x4 c01 = *(const f32x4*)(w1p + 4);
        f32x4 c10 = *(const f32x4*)(w1p + H1C);
        f32x4 c11 = *(const f32x4*)(w1p + H1C + 4);
        f32x4 c20 = *(const f32x4*)(w1p + 2 * H1C);
        f32x4 c21 = *(const f32x4*)(w1p + 2 * H1C + 4);
        f32x4 c30 = *(const f32x4*)(w1p + 3 * H1C);
        f32x4 c31 = *(const f32x4*)(w1p + 3 * H1C + 4);

        __builtin_amdgcn_s_setprio(1);   // favor GEMM-phase wave in issue arbitration
        #pragma unroll 2
        for (int k0 = 0; k0 < TWOD; k0 += 4) {
            f32x2 xp0[8], xp1[8];
            #pragma unroll
            for (int i = 0; i < 8; ++i) {
                f32x4 q = *(const f32x4*)&xb[r0 + i][k0];
                xp0[i] = LO2(q); xp1[i] = HI2(q);
            }
            const int kn = (k0 + 4) & 255;   // cyclic: last prefetch harmless
            const float* wnp = w1p + kn * H1C;
            f32x4 n00 = *(const f32x4*)(wnp);
            f32x4 n01 = *(const f32x4*)(wnp + 4);
            f32x4 n10 = *(const f32x4*)(wnp + H1C);
            f32x4 n11 = *(const f32x4*)(wnp + H1C + 4);
            f32x4 n20 = *(const f32x4*)(wnp + 2 * H1C);
            f32x4 n21 = *(const f32x4*)(wnp + 2 * H1C + 4);
            f32x4 n30 = *(const f32x4*)(wnp + 3 * H1C);
            f32x4 n31 = *(const f32x4*)(wnp + 3 * H1C + 4);

            f32x2 wA, wB;
            wA = LO2(c00); wB = HI2(c00);
            #pragma unroll
            for (int i = 0; i < 8; ++i) {
                pk_fma_b0(acc1[i][0], xp0[i], wA);
                pk_fma_b0(acc1[i][1], xp0[i], wB);
            }
            wA = LO2(c01); wB = HI2(c01);
            #pragma unroll
            for (int i = 0; i < 8; ++i) {
                pk_fma_b0(acc1[i][2], xp0[i], wA);
                pk_fma_b0(acc1[i][3], xp0[i], wB);
            }
            wA = LO2(c10); wB = HI2(c10);
            #pragma unroll
            for (int i = 0; i < 8; ++i) {
                pk_fma_b1(acc1[i][0], xp0[i], wA);
                pk_fma_b1(acc1[i][1], xp0[i], wB);
            }
            wA = LO2(c11); wB = HI2(c11);
            #pragma unroll
            for (int i = 0; i < 8; ++i) {
                pk_fma_b1(acc1[i][2], xp0[i], wA);
                pk_fma_b1(acc1[i][3], xp0[i], wB);
            }
            wA = LO2(c20); wB = HI2(c20);
            #pragma unroll
            for (int i = 0; i < 8; ++i) {
                pk_fma_b0(acc1[i][0], xp1[i], wA);
                pk_fma_b0(acc1[i][1], xp1[i], wB);
            }
            wA = LO2(c21); wB = HI2(c21);
            #pragma unroll
            for (int i = 0; i < 8; ++i) {
                pk_fma_b0(acc1[i][2], xp1[i], wA);
                pk_fma_b0(acc1[i][3], xp1[i], wB);
            }
            wA = LO2(c30); wB = HI2(c30);
            #pragma unroll
            for (int i = 0; i < 8; ++i) {
                pk_fma_b1(acc1[i][0], xp1[i], wA);
                pk_fma_b1(acc1[i][1], xp1[i], wB);
            }
            wA = LO2(c31); wB = HI2(c31);
            #pragma unroll
            for (int i = 0; i < 8; ++i) {
                pk_fma_b1(acc1[i][2], xp1[i], wA);
                pk_fma_b1(acc1[i][3], xp1[i], wB);
            }
            c00 = n00; c01 = n01; c10 = n10; c11 = n11;
            c20 = n20; c21 = n21; c30 = n30; c31 = n31;
        }
        __builtin_amdgcn_s_setprio(0);
    }
    __builtin_amdgcn_wave_barrier();   // fence: GEMM1 reads before LN1 writes

    // ---------------- bias + LN1 + ReLU (R8-proven) --------------------------
    {
        const float4 b1a = *(const float4*)(b1  + c1);
        const float4 b1b = *(const float4*)(b1  + c1 + 4);
        const float4 g1a = *(const float4*)(g1  + c1);
        const float4 g1b = *(const float4*)(g1  + c1 + 4);
        const float4 e1a = *(const float4*)(be1 + c1);
        const float4 e1b = *(const float4*)(be1 + c1 + 4);
        #pragma unroll
        for (int i = 0; i < 8; ++i) {
            float v[8];
            v[0] = acc1[i][0].x + b1a.x; v[1] = acc1[i][0].y + b1a.y;
            v[2] = acc1[i][1].x + b1a.z; v[3] = acc1[i][1].y + b1a.w;
            v[4] = acc1[i][2].x + b1b.x; v[5] = acc1[i][2].y + b1b.y;
            v[6] = acc1[i][3].x + b1b.z; v[7] = acc1[i][3].y + b1b.w;
            float s = 0.0f, ss = 0.0f;
            #pragma unroll
            for (int j = 0; j < 8; ++j) { s += v[j]; ss += v[j] * v[j]; }
            #pragma unroll
            for (int m = 1; m < 32; m <<= 1) {
                s  += __shfl_xor(s,  m, 32);
                ss += __shfl_xor(ss, m, 32);
            }
            const float mu  = s  * (1.0f / 256.0f);
            const float var = ss * (1.0f / 256.0f) - mu * mu;
            const float inv = 1.0f / sqrtf(var + EPSLN);
            float o[8];
            o[0] = fmaxf(0.0f, (v[0]-mu)*inv*g1a.x + e1a.x);
            o[1] = fmaxf(0.0f, (v[1]-mu)*inv*g1a.y + e1a.y);
            o[2] = fmaxf(0.0f, (v[2]-mu)*inv*g1a.z + e1a.z);
            o[3] = fmaxf(0.0f, (v[3]-mu)*inv*g1a.w + e1a.w);
            o[4] = fmaxf(0.0f, (v[4]-mu)*inv*g1b.x + e1b.x);
            o[5] = fmaxf(0.0f, (v[5]-mu)*inv*g1b.y + e1b.y);
            o[6] = fmaxf(0.0f, (v[6]-mu)*inv*g1b.z + e1b.z);
            o[7] = fmaxf(0.0f, (v[7]-mu)*inv*g1b.w + e1b.w);
            *(float4*)&xb[r0 + i][c1]     = make_float4(o[0], o[1], o[2], o[3]);
            *(float4*)&xb[r0 + i][c1 + 4] = make_float4(o[4], o[5], o[6], o[7]);
        }
    }
    __builtin_amdgcn_wave_barrier();   // fence: LN1 writes before GEMM2 reads

    // ---------------- GEMM2: 8 rows x 4 cols (R8-proven) ---------------------
    f32x2 acc2[8][2];
    #pragma unroll
    for (int i = 0; i < 8; ++i) {
        acc2[i][0] = f32x2{0.0f, 0.0f};
        acc2[i][1] = f32x2{0.0f, 0.0f};
    }

    const int c2 = cb * 4;
    {
        const float* __restrict__ w2p = W2 + c2;
        f32x4 d0 = *(const f32x4*)(w2p);
        f32x4 d1 = *(const f32x4*)(w2p + H2C);
        f32x4 d2 = *(const f32x4*)(w2p + 2 * H2C);
        f32x4 d3 = *(const f32x4*)(w2p + 3 * H2C);

        __builtin_amdgcn_s_setprio(1);
        #pragma unroll 2
        for (int k0 = 0; k0 < TWOD; k0 += 4) {
            f32x2 xp0[8], xp1[8];
            #pragma unroll
            for (int i = 0; i < 8; ++i) {
                f32x4 q = *(const f32x4*)&xb[r0 + i][k0];
                xp0[i] = LO2(q); xp1[i] = HI2(q);
            }
            const int kn = (k0 + 4) & 255;
            const float* wnp = w2p + kn * H2C;
            f32x4 m0 = *(const f32x4*)(wnp);
            f32x4 m1 = *(const f32x4*)(wnp + H2C);
            f32x4 m2 = *(const f32x4*)(wnp + 2 * H2C);
            f32x4 m3 = *(const f32x4*)(wnp + 3 * H2C);

            f32x2 wA, wB;
            wA = LO2(d0); wB = HI2(d0);
            #pragma unroll
            for (int i = 0; i < 8; ++i) {
                pk_fma_b0(acc2[i][0], xp0[i], wA);
                pk_fma_b0(acc2[i][1], xp0[i], wB);
            }
            wA = LO2(d1); wB = HI2(d1);
            #pragma unroll
            for (int i = 0; i < 8; ++i) {
                pk_fma_b1(acc2[i][0], xp0[i], wA);
                pk_fma_b1(acc2[i][1], xp0[i], wB);
            }
            wA = LO2(d2); wB = HI2(d2);
            #pragma unroll
            for (int i = 0; i < 8; ++i) {
                pk_fma_b0(acc2[i][0], xp1[i], wA);
                pk_fma_b0(acc2[i][1], xp1[i], wB);
            }
            wA = LO2(d3); wB = HI2(d3);
            #pragma unroll
            for (int i = 0; i < 8; ++i) {
                pk_fma_b1(acc2[i][0], xp1[i], wA);
                pk_fma_b1(acc2[i][1], xp1[i], wB);
            }
            d0 = m0; d1 = m1; d2 = m2; d3 = m3;
        }
        __builtin_amdgcn_s_setprio(0);
    }

    // ---------------- bias + LN2 + ReLU + heads + outputs (R8-proven) --------
    {
        const float4 b2v = *(const float4*)(b2  + c2);
        const float4 g2v = *(const float4*)(g2  + c2);
        const float4 e2v = *(const float4*)(be2 + c2);
        const float4 wpv = *(const float4*)(Wp  + c2);
        const float4 wwv = *(const float4*)(Ww  + c2);
        const float ww128 = Ww[DD];
        const float bpv = bp[0], bwv = bw[0];
        const float wn = wnode[0], wbr = wnbr[0];
        #pragma unroll
        for (int i = 0; i < 8; ++i) {
            float v0 = acc2[i][0].x + b2v.x;
            float v1 = acc2[i][0].y + b2v.y;
            float v2 = acc2[i][1].x + b2v.z;
            float v3 = acc2[i][1].y + b2v.w;
            float s  = v0 + v1 + v2 + v3;
            float ss = v0*v0 + v1*v1 + v2*v2 + v3*v3;
            #pragma unroll
            for (int m = 1; m < 32; m <<= 1) {
                s  += __shfl_xor(s,  m, 32);
                ss += __shfl_xor(ss, m, 32);
            }
            const float mu  = s  * (1.0f / 128.0f);
            const float var = ss * (1.0f / 128.0f) - mu * mu;
            const float inv = 1.0f / sqrtf(var + EPSLN);
            const float h0  = fmaxf(0.0f, (v0-mu)*inv*g2v.x + e2v.x);
            const float h1v = fmaxf(0.0f, (v1-mu)*inv*g2v.y + e2v.y);
            const float h2v = fmaxf(0.0f, (v2-mu)*inv*g2v.z + e2v.z);
            const float h3  = fmaxf(0.0f, (v3-mu)*inv*g2v.w + e2v.w);
            float pdot = h0*wpv.x + h1v*wpv.y + h2v*wpv.z + h3*wpv.w;
            float wdot = h0*wwv.x + h1v*wwv.y + h2v*wwv.z + h3*wwv.w;
            #pragma unroll
            for (int m = 1; m < 32; m <<= 1) {
                pdot += __shfl_xor(pdot, m, 32);
                wdot += __shfl_xor(wdot, m, 32);
            }
            if (cb == 0) {
                const int e  = e0 + r0 + i;
                const float ns   = nbsim[r0 + i];
                const float nc   = (pdot + bpv) * wn;
                const float nbc  = ns * wbr;
                const float prob = nc + nbc;
                out[e]          = prob;
                out[NE + e]     = fmaxf(0.0f, wdot + ns * ww128 + bwv);
                out[2 * NE + e] = nc / (prob + 1e-8f);
            }
        }
    }
}

extern "C" void kernel_launch(void* const* d_in, const int* in_sizes, int n_in,
                              void* d_out, int out_size, void* d_ws, size_t ws_size,
                              hipStream_t stream) {
    const float* nodes = (const float*)d_in[0];
    const float* nbrs  = (const float*)d_in[1];
    const int*   eidx  = (const int*)d_in[2];
    const float* g0    = (const float*)d_in[3];
    const float* be0   = (const float*)d_in[4];
    const float* W1    = (const float*)d_in[5];
    const float* b1    = (const float*)d_in[6];
    const float* g1    = (const float*)d_in[7];
    const float* be1   = (const float*)d_in[8];
    const float* W2    = (const float*)d_in[9];
    const float* b2    = (const float*)d_in[10];
    const float* g2    = (const float*)d_in[11];
    const float* be2   = (const float*)d_in[12];
    const float* Wp    = (const float*)d_in[13];
    const float* bp    = (const float*)d_in[14];
    const float* Ww    = (const float*)d_in[15];
    const float* bw    = (const float*)d_in[16];
    const float* wnode = (const float*)d_in[17];
    const float* wnbr  = (const float*)d_in[18];
    float* out = (float*)d_out;

    dim3 grid(NE / EB), block(256);
    decoder_fused<<<grid, block, 0, stream>>>(nodes, nbrs, eidx, g0, be0,
                                              W1, b1, g1, be1, W2, b2, g2, be2,
                                              Wp, bp, Ww, bw, wnode, wnbr, out);
}